// Round 14
// baseline (9206.595 us; speedup 1.0000x reference)
//
#include <hip/hip_runtime.h>
#include <hip/hip_fp16.h>
#include <stdint.h>

// Reservoir recurrence, persistent-wave dataflow, round 14.
//   s_{t+1} = tanh(u_t + 0.9 * W_res @ s_t) / sqrt(2048)
// Base = round 9 exactly (best: 6440 us). ONE isolated change: per-wave
// publish -- each wave's lanes 0/2 store its two adjacent tagged units right
// after tanh; barrier2 and the `ous` gather are deleted. Correctness: unit
// tagged t+1 => its wave passed barrier1(t) and its t-reads are complete
// (data dependence); a t+2 overwrite requires ALL t+1 tags => every wave's
// t-reads done and no one still polls t. pay[] WAR is covered by barrier1.
// (R7/R12 ran per-wave publish only alongside spill/AGPR confounds; R13's
// two-stream poll was a clean null -> reverted to single-stream.)

#define RES     2048
#define ROWSPW  4                    // rows per wave
#define WPB     8                    // waves per block
#define ROWSPB  (ROWSPW * WPB)       // 32 rows per block
#define NBLK    (RES / ROWSPB)       // 64 blocks
#define NUNITS  (RES / 2)            // 1024 8-byte exchange units
#define UPW     (NUNITS / WPB / 64)  // 2 unit-loads per lane per poll round
#define KPL     (RES / 2 / 64)       // 16 u32 weight words per lane per row
#define CHK     (KPL / 4)            // 4 b128 chunks per lane per row

typedef _Float16 half2v __attribute__((ext_vector_type(2)));

union H2U { half2v h; uint32_t u; };

__device__ __forceinline__ uint32_t pack_h2(float a, float b) {
  H2U c; c.h.x = (_Float16)a; c.h.y = (_Float16)b; return c.u;
}
__device__ __forceinline__ half2v u_to_h2(uint32_t u) { H2U c; c.u = u; return c.h; }

__device__ __forceinline__ float dot2acc(uint32_t wu, uint32_t su, float acc) {
#if __has_builtin(__builtin_amdgcn_fdot2)
  return __builtin_amdgcn_fdot2(u_to_h2(wu), u_to_h2(su), acc, false);
#else
  half2v w = u_to_h2(wu), s = u_to_h2(su);
  acc = fmaf((float)w.x, (float)s.x, acc);
  return fmaf((float)w.y, (float)s.y, acc);
#endif
}

__device__ __forceinline__ float fast_tanh(float x) {
  // tanh(x) = 1 - 2/(e^{2x}+1); saturates to exactly +-1 on over/underflow.
  float e = __expf(2.0f * x);
  return 1.0f - 2.0f / (e + 1.0f);
}

__device__ __forceinline__ float merge_red(float lo, float hi, int mask, int lane) {
  // Lanes with (lane&mask)==0 end up carrying lo's pair-sum, others hi's.
  float sel  = (lane & mask) ? lo : hi;
  float keep = (lane & mask) ? hi : lo;
  return keep + __shfl_xor(sel, mask);
}

__global__ void reservoir_init(const float* __restrict__ s0,
                               float* __restrict__ out,
                               uint64_t* __restrict__ buf0,
                               uint64_t* __restrict__ buf1,
                               int res) {
  int i = blockIdx.x * blockDim.x + threadIdx.x;
  if (i < res) out[i] = s0[i];            // output row 0 = initial_state (f32)
  if (i < res / 2) {
    uint32_t a = (uint32_t)__half_as_ushort(__float2half_rn(s0[2 * i]));
    uint32_t b = (uint32_t)__half_as_ushort(__float2half_rn(s0[2 * i + 1]));
    buf0[i] = (uint64_t)(a | (b << 16));  // payload low, tag 0 high
    buf1[i] = 0xFFFFFFFF00000000ull;      // poison tag (never matches 0..4096)
  }
}

__global__ void __launch_bounds__(512, 1)
reservoir_main(const float* __restrict__ in,     // (seq, isz) f32
               const float* __restrict__ W_in,   // (RES, isz) f32
               const float* __restrict__ W_res,  // (RES, RES) f32
               float* __restrict__ out,          // (seq+1, RES) f32
               uint64_t* __restrict__ buf0,
               uint64_t* __restrict__ buf1,
               int seq, int isz) {
  const int lane = threadIdx.x & 63;
  const int q    = threadIdx.x >> 6;              // wave index in block, 0..7
  const int W    = blockIdx.x * WPB + q;          // global wave id, 0..511
  const int r0   = W * ROWSPW;                    // first owned state row

  // LDS: 128 KB weights + 8 KB pay = ~136 KB (1 block/CU).
  __shared__ uint32_t wlds[ROWSPB * (RES / 2)];   // [32 rows][1024 half2]
  __shared__ uint32_t pay[2][NUNITS];             // staged payloads per parity

  // ---- one-time: stage this wave's 4 rows into LDS as f16 pairs, x0.9.
#pragma unroll
  for (int r = 0; r < ROWSPW; ++r) {
    const int lr = q * ROWSPW + r;                // local row in block
    const float* wr = W_res + (size_t)(r0 + r) * RES;
    uint32_t* wl = &wlds[lr * (RES / 2)];
#pragma unroll
    for (int jj = 0; jj < KPL; ++jj) {
      int k = lane + 64 * jj;
      float2 p2 = *(const float2*)(wr + 2 * k);
      wl[k] = pack_h2(0.9f * p2.x, 0.9f * p2.y);
    }
  }
  // (no barrier needed: each wave reads only the rows it wrote)

  // W_in slice: lane l holds input columns 2l, 2l+1 for its 4 rows (f32).
  float win[ROWSPW][2];
#pragma unroll
  for (int r = 0; r < ROWSPW; ++r) {
    float2 p2 = *(const float2*)(W_in + (size_t)(r0 + r) * isz + 2 * lane);
    win[r][0] = p2.x;
    win[r][1] = p2.y;
  }

  const float inv_sqrt_n = 0.022097086912079612f;  // 1/sqrt(2048)

  // prefetch input row 0 (lane l -> cols 2l, 2l+1)
  float2 xin = *(const float2*)(in + 2 * lane);

  const int ubase = q * (NUNITS / WPB) + lane;     // this wave's poll slice

  for (int t = 0; t < seq; ++t) {
    const int p = t & 1;
    const uint64_t* src = p ? buf1 : buf0;  // holds s_t (tag == t)
    uint64_t* dst       = p ? buf0 : buf1;  // will hold s_{t+1}
    const uint32_t want = (uint32_t)t;

    // ---- issue the step's weight reads FIRST (state-independent): 16 x
    // ds_read_b128 into registers; they stream over the LDS port while the
    // wave polls below (R9 form -- no keep-alive asm).
    uint4 wv[ROWSPW][CHK];
#pragma unroll
    for (int r = 0; r < ROWSPW; ++r)
#pragma unroll
      for (int m = 0; m < CHK; ++m)
        wv[r][m] = *reinterpret_cast<const uint4*>(
            &wlds[(q * ROWSPW + r) * (RES / 2) + 4 * (lane + 64 * m)]);
    __builtin_amdgcn_sched_barrier(0);

    // ---- poll this wave's slice: 2 batched 8B loads, single wait
    uint32_t dw[UPW];
    for (;;) {
      uint64_t v[UPW];
#pragma unroll
      for (int k = 0; k < UPW; ++k)
        v[k] = __hip_atomic_load(src + ubase + 64 * k, __ATOMIC_RELAXED,
                                 __HIP_MEMORY_SCOPE_AGENT);
      bool ok = true;
#pragma unroll
      for (int k = 0; k < UPW; ++k)
        ok &= ((uint32_t)(v[k] >> 32) == want);
      if (__all(ok)) {
#pragma unroll
        for (int k = 0; k < UPW; ++k) dw[k] = (uint32_t)v[k];
        break;
      }
    }

    // ---- stage validated payloads in LDS; barrier publishes them block-wide
#pragma unroll
    for (int k = 0; k < UPW; ++k)
      pay[p][ubase + 64 * k] = dw[k];
    __syncthreads();

    // ---- accumulators start with the input projection (INPUT_SCALE = 1)
    float acc[ROWSPW];
#pragma unroll
    for (int r = 0; r < ROWSPW; ++r)
      acc[r] = fmaf(xin.y, win[r][1], xin.x * win[r][0]);

    // ---- matvec: per chunk m, one uint4 of state (8 cols) shared across the
    // wave's 4 rows; weights from the prefetched registers.
#pragma unroll
    for (int m = 0; m < CHK; ++m) {
      const int ki = 4 * (lane + 64 * m);
      uint4 sv = *reinterpret_cast<const uint4*>(&pay[p][ki]);
#pragma unroll
      for (int r = 0; r < ROWSPW; ++r) {
        acc[r] = dot2acc(wv[r][m].x, sv.x, acc[r]);
        acc[r] = dot2acc(wv[r][m].y, sv.y, acc[r]);
        acc[r] = dot2acc(wv[r][m].z, sv.z, acc[r]);
        acc[r] = dot2acc(wv[r][m].w, sv.w, acc[r]);
      }
    }

    // ---- merged butterfly: 7 shfls; lane l ends holding row r0 + (l & 3)
    float m0 = merge_red(acc[0], acc[1], 1, lane);
    float m1 = merge_red(acc[2], acc[3], 1, lane);
    float qq = merge_red(m0, m1, 2, lane);
    qq += __shfl_xor(qq, 4);
    qq += __shfl_xor(qq, 8);
    qq += __shfl_xor(qq, 16);
    qq += __shfl_xor(qq, 32);

    float o = fast_tanh(qq) * inv_sqrt_n;

    // ---- per-wave publish, immediately after tanh (no second barrier):
    // lanes 0/2 store the wave's two ADJACENT tagged units in one exec-masked
    // store instruction (8B apart -> one 16B coalesced transaction).
    uint32_t hu = (uint32_t)__half_as_ushort(__float2half_rn(o));
    uint32_t up = (uint32_t)__shfl_xor((int)hu, 1);     // partner row's half
    uint32_t word = (hu & 0xffffu) | (up << 16);        // valid on even lanes
    uint64_t val  = ((uint64_t)(uint32_t)(t + 1) << 32) | (uint64_t)word;
    if (lane == 0 || lane == 2)
      __hip_atomic_store(dst + 2 * W + (lane >> 1), val, __ATOMIC_RELAXED,
                         __HIP_MEMORY_SCOPE_AGENT);

    // ---- off the critical path: f32 output row, next input prefetch
    if (lane < ROWSPW)
      out[(size_t)(t + 1) * RES + r0 + lane] = o;
    int tn = (t + 1 < seq) ? (t + 1) : t;
    xin = *(const float2*)(in + (size_t)tn * isz + 2 * lane);
  }
}

extern "C" void kernel_launch(void* const* d_in, const int* in_sizes, int n_in,
                              void* d_out, int out_size, void* d_ws, size_t ws_size,
                              hipStream_t stream) {
  const float* input = (const float*)d_in[0];   // (seq, isz)
  const float* s0    = (const float*)d_in[1];   // (res,)
  const float* W_in  = (const float*)d_in[2];   // (res, isz)
  const float* W_res = (const float*)d_in[3];   // (res, res)
  float* out = (float*)d_out;

  const int res = in_sizes[1];             // 2048
  const int isz = in_sizes[2] / res;       // 128
  const int seq = in_sizes[0] / isz;       // 4096

  uint64_t* buf0 = (uint64_t*)d_ws;        // res/2 units
  uint64_t* buf1 = buf0 + res / 2;         // res/2 units (16 KB total)

  reservoir_init<<<(res + 255) / 256, 256, 0, stream>>>(s0, out, buf0, buf1, res);
  reservoir_main<<<NBLK, WPB * 64, 0, stream>>>(input, W_in, W_res, out,
                                                buf0, buf1, seq, isz);
}

// Round 15
// 6389.286 us; speedup vs baseline: 1.4409x; 1.4409x over previous
//
#include <hip/hip_runtime.h>
#include <hip/hip_fp16.h>
#include <stdint.h>

// Reservoir recurrence, persistent-wave dataflow, round 15 = round 9 restore.
//   s_{t+1} = tanh(u_t + 0.9 * W_res @ s_t) / sqrt(2048)
// Champion configuration (6440 us, 1.57 us/step):
//  - one-hop fused exchange: 8B unit = (2 x f16 state | u32 step tag), one
//    relaxed agent-scope 64-bit atomic store; consumers validate by tag;
//    double-buffered by step parity (no fences, no release, no sleeps)
//  - 64 blocks x 8 waves; weights in LDS (128 KB/block, f16 pairs x0.9),
//    issued as 16 x ds_read_b128 BEFORE the poll (streams during the wait)
//  - wave-sliced poll (2 batched 8B loads/lane), LDS stage + barrier1
//  - merged 7-shfl butterfly reduction
//  - block-coalesced publish: wave 0 stores 16 tagged units (one 128B line)
// Falsified levers (do not revisit): VGPR/AGPR weight residency (R4,R7,R11,
// R12 - allocator spills all mechanisms), DVFS heaters (R6), two-stream poll
// (R13), per-wave publish (R7/R12/R14 - MALL partial-line RMW penalty),
// split flags/data + release + sleep (R2).

#define RES     2048
#define ROWSPW  4                    // rows per wave
#define WPB     8                    // waves per block
#define ROWSPB  (ROWSPW * WPB)       // 32 rows per block
#define NBLK    (RES / ROWSPB)       // 64 blocks
#define NUNITS  (RES / 2)            // 1024 8-byte exchange units
#define UPB     (ROWSPB / 2)         // 16 units published per block
#define UPW     (NUNITS / WPB / 64)  // 2 unit-loads per lane per poll round
#define KPL     (RES / 2 / 64)       // 16 u32 weight words per lane per row
#define CHK     (KPL / 4)            // 4 b128 chunks per lane per row

typedef _Float16 half2v __attribute__((ext_vector_type(2)));

union H2U { half2v h; uint32_t u; };

__device__ __forceinline__ uint32_t pack_h2(float a, float b) {
  H2U c; c.h.x = (_Float16)a; c.h.y = (_Float16)b; return c.u;
}
__device__ __forceinline__ half2v u_to_h2(uint32_t u) { H2U c; c.u = u; return c.h; }

__device__ __forceinline__ float dot2acc(uint32_t wu, uint32_t su, float acc) {
#if __has_builtin(__builtin_amdgcn_fdot2)
  return __builtin_amdgcn_fdot2(u_to_h2(wu), u_to_h2(su), acc, false);
#else
  half2v w = u_to_h2(wu), s = u_to_h2(su);
  acc = fmaf((float)w.x, (float)s.x, acc);
  return fmaf((float)w.y, (float)s.y, acc);
#endif
}

__device__ __forceinline__ float fast_tanh(float x) {
  // tanh(x) = 1 - 2/(e^{2x}+1); saturates to exactly +-1 on over/underflow.
  float e = __expf(2.0f * x);
  return 1.0f - 2.0f / (e + 1.0f);
}

__device__ __forceinline__ float merge_red(float lo, float hi, int mask, int lane) {
  // Lanes with (lane&mask)==0 end up carrying lo's pair-sum, others hi's.
  float sel  = (lane & mask) ? lo : hi;
  float keep = (lane & mask) ? hi : lo;
  return keep + __shfl_xor(sel, mask);
}

__global__ void reservoir_init(const float* __restrict__ s0,
                               float* __restrict__ out,
                               uint64_t* __restrict__ buf0,
                               uint64_t* __restrict__ buf1,
                               int res) {
  int i = blockIdx.x * blockDim.x + threadIdx.x;
  if (i < res) out[i] = s0[i];            // output row 0 = initial_state (f32)
  if (i < res / 2) {
    uint32_t a = (uint32_t)__half_as_ushort(__float2half_rn(s0[2 * i]));
    uint32_t b = (uint32_t)__half_as_ushort(__float2half_rn(s0[2 * i + 1]));
    buf0[i] = (uint64_t)(a | (b << 16));  // payload low, tag 0 high
    buf1[i] = 0xFFFFFFFF00000000ull;      // poison tag (never matches 0..4096)
  }
}

__global__ void __launch_bounds__(512, 1)
reservoir_main(const float* __restrict__ in,     // (seq, isz) f32
               const float* __restrict__ W_in,   // (RES, isz) f32
               const float* __restrict__ W_res,  // (RES, RES) f32
               float* __restrict__ out,          // (seq+1, RES) f32
               uint64_t* __restrict__ buf0,
               uint64_t* __restrict__ buf1,
               int seq, int isz) {
  const int lane = threadIdx.x & 63;
  const int q    = threadIdx.x >> 6;              // wave index in block, 0..7
  const int W    = blockIdx.x * WPB + q;          // global wave id, 0..511
  const int r0   = W * ROWSPW;                    // first owned state row

  // LDS: 128 KB weights + 8 KB pay + publish gather = ~139 KB (1 block/CU).
  __shared__ uint32_t wlds[ROWSPB * (RES / 2)];   // [32 rows][1024 half2]
  __shared__ uint32_t pay[2][NUNITS];             // staged payloads per parity
  __shared__ uint32_t ous[UPB];                   // block publish gather

  // ---- one-time: stage this wave's 4 rows into LDS as f16 pairs, x0.9.
#pragma unroll
  for (int r = 0; r < ROWSPW; ++r) {
    const int lr = q * ROWSPW + r;                // local row in block
    const float* wr = W_res + (size_t)(r0 + r) * RES;
    uint32_t* wl = &wlds[lr * (RES / 2)];
#pragma unroll
    for (int jj = 0; jj < KPL; ++jj) {
      int k = lane + 64 * jj;
      float2 p2 = *(const float2*)(wr + 2 * k);
      wl[k] = pack_h2(0.9f * p2.x, 0.9f * p2.y);
    }
  }
  // (no barrier needed: each wave reads only the rows it wrote)

  // W_in slice: lane l holds input columns 2l, 2l+1 for its 4 rows (f32).
  float win[ROWSPW][2];
#pragma unroll
  for (int r = 0; r < ROWSPW; ++r) {
    float2 p2 = *(const float2*)(W_in + (size_t)(r0 + r) * isz + 2 * lane);
    win[r][0] = p2.x;
    win[r][1] = p2.y;
  }

  const float inv_sqrt_n = 0.022097086912079612f;  // 1/sqrt(2048)

  // prefetch input row 0 (lane l -> cols 2l, 2l+1)
  float2 xin = *(const float2*)(in + 2 * lane);

  const int ubase = q * (NUNITS / WPB) + lane;     // this wave's poll slice

  for (int t = 0; t < seq; ++t) {
    const int p = t & 1;
    const uint64_t* src = p ? buf1 : buf0;  // holds s_t (tag == t)
    uint64_t* dst       = p ? buf0 : buf1;  // will hold s_{t+1}
    const uint32_t want = (uint32_t)t;

    // ---- issue the step's weight reads FIRST (state-independent): 16 x
    // ds_read_b128 into registers; they stream over the LDS port while the
    // wave polls below. lgkmcnt-wait lands at first use (after the barrier).
    uint4 wv[ROWSPW][CHK];
#pragma unroll
    for (int r = 0; r < ROWSPW; ++r)
#pragma unroll
      for (int m = 0; m < CHK; ++m)
        wv[r][m] = *reinterpret_cast<const uint4*>(
            &wlds[(q * ROWSPW + r) * (RES / 2) + 4 * (lane + 64 * m)]);
    __builtin_amdgcn_sched_barrier(0);

    // ---- poll this wave's slice: 2 batched 8B loads, single wait
    uint32_t dw[UPW];
    for (;;) {
      uint64_t v[UPW];
#pragma unroll
      for (int k = 0; k < UPW; ++k)
        v[k] = __hip_atomic_load(src + ubase + 64 * k, __ATOMIC_RELAXED,
                                 __HIP_MEMORY_SCOPE_AGENT);
      bool ok = true;
#pragma unroll
      for (int k = 0; k < UPW; ++k)
        ok &= ((uint32_t)(v[k] >> 32) == want);
      if (__all(ok)) {
#pragma unroll
        for (int k = 0; k < UPW; ++k) dw[k] = (uint32_t)v[k];
        break;
      }
    }

    // ---- stage validated payloads in LDS; barrier publishes them block-wide
#pragma unroll
    for (int k = 0; k < UPW; ++k)
      pay[p][ubase + 64 * k] = dw[k];
    __syncthreads();

    // ---- accumulators start with the input projection (INPUT_SCALE = 1)
    float acc[ROWSPW];
#pragma unroll
    for (int r = 0; r < ROWSPW; ++r)
      acc[r] = fmaf(xin.y, win[r][1], xin.x * win[r][0]);

    // ---- matvec: per chunk m, one uint4 of state (8 cols) shared across the
    // wave's 4 rows; weights from the prefetched registers.
#pragma unroll
    for (int m = 0; m < CHK; ++m) {
      const int ki = 4 * (lane + 64 * m);
      uint4 sv = *reinterpret_cast<const uint4*>(&pay[p][ki]);
#pragma unroll
      for (int r = 0; r < ROWSPW; ++r) {
        acc[r] = dot2acc(wv[r][m].x, sv.x, acc[r]);
        acc[r] = dot2acc(wv[r][m].y, sv.y, acc[r]);
        acc[r] = dot2acc(wv[r][m].z, sv.z, acc[r]);
        acc[r] = dot2acc(wv[r][m].w, sv.w, acc[r]);
      }
    }

    // ---- merged butterfly: 7 shfls; lane l ends holding row r0 + (l & 3)
    float m0 = merge_red(acc[0], acc[1], 1, lane);
    float m1 = merge_red(acc[2], acc[3], 1, lane);
    float qq = merge_red(m0, m1, 2, lane);
    qq += __shfl_xor(qq, 4);
    qq += __shfl_xor(qq, 8);
    qq += __shfl_xor(qq, 16);
    qq += __shfl_xor(qq, 32);

    float o = fast_tanh(qq) * inv_sqrt_n;

    // ---- gather the block's 32 rows (16 packed u32) into LDS
    uint32_t hu = (uint32_t)__half_as_ushort(__float2half_rn(o));
    uint32_t up = (uint32_t)__shfl_xor((int)hu, 1);     // partner row's half
    uint32_t word = (hu & 0xffffu) | (up << 16);        // valid on even lanes
    if (lane == 0 || lane == 2)
      ous[2 * q + (lane >> 1)] = word;

    // f32 output row (off the critical path, before the barrier)
    if (lane < ROWSPW)
      out[(size_t)(t + 1) * RES + r0 + lane] = o;

    __syncthreads();

    // ---- publish: wave 0 stores the block's 16 tagged units (one 128B
    // line; 64 MALL write transactions grid-wide -- scattered per-wave
    // stores trigger partial-line RMW fetches, R14). No WAR on `ous`:
    // nobody passes the next poll until this store is visible, and the
    // store reads ous first.
    if (q == 0 && lane < UPB) {
      uint64_t val = ((uint64_t)(uint32_t)(t + 1) << 32) | (uint64_t)ous[lane];
      __hip_atomic_store(dst + UPB * blockIdx.x + lane, val, __ATOMIC_RELAXED,
                         __HIP_MEMORY_SCOPE_AGENT);
    }

    // prefetch next input row
    int tn = (t + 1 < seq) ? (t + 1) : t;
    xin = *(const float2*)(in + (size_t)tn * isz + 2 * lane);
  }
}

extern "C" void kernel_launch(void* const* d_in, const int* in_sizes, int n_in,
                              void* d_out, int out_size, void* d_ws, size_t ws_size,
                              hipStream_t stream) {
  const float* input = (const float*)d_in[0];   // (seq, isz)
  const float* s0    = (const float*)d_in[1];   // (res,)
  const float* W_in  = (const float*)d_in[2];   // (res, isz)
  const float* W_res = (const float*)d_in[3];   // (res, res)
  float* out = (float*)d_out;

  const int res = in_sizes[1];             // 2048
  const int isz = in_sizes[2] / res;       // 128
  const int seq = in_sizes[0] / isz;       // 4096

  uint64_t* buf0 = (uint64_t*)d_ws;        // res/2 units
  uint64_t* buf1 = buf0 + res / 2;         // res/2 units (16 KB total)

  reservoir_init<<<(res + 255) / 256, 256, 0, stream>>>(s0, out, buf0, buf1, res);
  reservoir_main<<<NBLK, WPB * 64, 0, stream>>>(input, W_in, W_res, out,
                                                buf0, buf1, seq, isz);
}